// Round 10
// baseline (136.331 us; speedup 1.0000x reference)
//
#include <hip/hip_runtime.h>
#include <hip/hip_bf16.h>

typedef _Float16 half8v __attribute__((ext_vector_type(8)));
typedef _Float16 half4v __attribute__((ext_vector_type(4)));
typedef _Float16 half2v __attribute__((ext_vector_type(2)));
typedef __fp16   fp16x2 __attribute__((ext_vector_type(2)));
typedef __attribute__((ext_vector_type(4))) float floatx4;

#define LOG2E_OVER_8 0.18033688011112042f

// bare v_exp_f32 (scores are bounded: ocml's denorm/range fixup is dead work)
#if __has_builtin(__builtin_amdgcn_exp2f)
#define EXP2(x) __builtin_amdgcn_exp2f(x)
#else
#define EXP2(x) exp2f(x)
#endif

// ===== Frag-order layouts (verified r9-r17) =================================
// Kh chunk(t16,c): ((t16*2+c)*64 + quad*16 + m)*8 halves  (A-frag 16x16x32)
// Qh: same with m=q%16. Vh chunk(t64,dt,ktp): (((t64*8)+dt*2+ktp)*64+quad*16+m)*8
// Wt: ((ctg*16+kc)*64 + quad*16 + m)*8
// PV k-permutation (verified r19): kappa(quad,j) identical on P and V -> one
// mfma_16x16x32 computes the 32-key PV exactly.
//
// SESSION LEDGER (measured): LDS staging ~neutral (r18/r22); PV@K32+ones-den
// -3.7us (r19); lb(256,4)+setprio+direct -5.1us (r20); bare EXP2 -4.7us (r21);
// spl 8->4 neutral (r23); 16-row proj +5us REGRESS (r24); lb(256,6) spill
// disaster +17us (r25); r26 revert = 122.07us best. THIS ROUND: latency-chain
// theory (3.6x amplification of every issue-cut; all memory theories dead):
// flat half-tile software pipeline, qt=1: loads(h+1) -> exp(h) -> QK(h+1) ->
// PV(h). Decision rule: >=121.5 -> revert & declare roofline.

// ---------------- Kernel 0: W -> frag-order Wt fp16 -------------------------
__global__ __launch_bounds__(256) void wtrans_k(const float* __restrict__ Wq,
                                                const float* __restrict__ Wk,
                                                const float* __restrict__ Wv,
                                                _Float16* __restrict__ Wt) {
    int idx = blockIdx.x * 256 + threadIdx.x;   // 98304 = 3*512*64
    int p = idx >> 15, rem = idx & 32767;
    int k = rem >> 6;      // input row
    int n = rem & 63;      // input col (lane-fast -> coalesced read)
    const float* W = (p == 0) ? Wq : ((p == 1) ? Wk : Wv);
    int ctg = p * 4 + (n >> 4), m = n & 15;
    int kc = k >> 5, quad = (k >> 3) & 3, j = k & 7;
    Wt[(((ctg << 4) + kc) * 64 + (quad << 4) + m) * 8 + j] = (_Float16)W[k * 64 + n];
}

// ---------------- Kernel 1: QKV projection, 32-row blocks (r16 verbatim) ----
#define XS_STRIDE 536
__global__ __launch_bounds__(256) void proj_k(const float* __restrict__ x,
                                              const _Float16* __restrict__ Wt,
                                              const float* __restrict__ bq,
                                              const float* __restrict__ bk,
                                              const float* __restrict__ bv,
                                              _Float16* __restrict__ Qh,
                                              _Float16* __restrict__ Kh,
                                              _Float16* __restrict__ Vh) {
    __shared__ _Float16 xs[2][16 * XS_STRIDE];   // 34.3 KB

    int tid = threadIdx.x, l = tid & 63, wv = tid >> 6;
    int m = l & 15, quad = l >> 4;
    int row0 = blockIdx.x * 32;

#pragma unroll
    for (int s = 0; s < 2; s++)
#pragma unroll
        for (int i = 0; i < 8; i++) {
            int idx = tid + i * 256;
            int row = idx >> 7, c4 = idx & 127;
            float4 v = *(const float4*)(x + (row0 + s * 16 + row) * 512 + c4 * 4);
            union { half2v h[2]; uint2 u; } cv;
            cv.h[0][0] = (_Float16)v.x; cv.h[0][1] = (_Float16)v.y;
            cv.h[1][0] = (_Float16)v.z; cv.h[1][1] = (_Float16)v.w;
            *(uint2*)(xs[s] + row * XS_STRIDE + c4 * 4) = cv.u;
        }
    __syncthreads();

    const _Float16* arow0 = xs[0] + m * XS_STRIDE + quad * 8;
    const _Float16* arow1 = xs[1] + m * XS_STRIDE + quad * 8;

    floatx4 acc[2][3];
#pragma unroll
    for (int s = 0; s < 2; s++)
#pragma unroll
        for (int i = 0; i < 3; i++) acc[s][i] = (floatx4)(0.f);

#pragma unroll 4
    for (int kc = 0; kc < 16; kc++) {
        half8v a0 = *(const half8v*)(arow0 + kc * 32);
        half8v a1 = *(const half8v*)(arow1 + kc * 32);
#pragma unroll
        for (int ct = 0; ct < 3; ct++) {
            int ctg = wv * 3 + ct;
            half8v b = *(const half8v*)(Wt + (((ctg << 4) + kc) * 64 + l) * 8);
            acc[0][ct] = __builtin_amdgcn_mfma_f32_16x16x32_f16(a0, b, acc[0][ct], 0, 0, 0);
            acc[1][ct] = __builtin_amdgcn_mfma_f32_16x16x32_f16(a1, b, acc[1][ct], 0, 0, 0);
        }
    }

#pragma unroll
    for (int s = 0; s < 2; s++) {
        int rowb = row0 + s * 16;
#pragma unroll
        for (int ct = 0; ct < 3; ct++) {
            int ctg = wv * 3 + ct;
            int col = ctg * 16 + m;
            float bias = (ctg < 4) ? bq[col] : ((ctg < 8) ? bk[col - 64] : bv[col - 128]);
            if (ctg < 8) {
                _Float16* dst = (ctg < 4) ? Qh : Kh;
                float scl = (ctg < 4) ? LOG2E_OVER_8 : 1.0f;
                int dd = (ctg & 3) * 16 + m;
                int c = dd >> 5, quadQ = (dd >> 3) & 3, j = dd & 7;
#pragma unroll
                for (int r = 0; r < 4; r++) {
                    int row = rowb + quad * 4 + r;
                    int chunk = ((row >> 4) << 1) + c;
                    dst[(chunk * 64 + quadQ * 16 + (row & 15)) * 8 + j] =
                        (_Float16)((acc[s][ct][r] + bias) * scl);
                }
            } else {
                int dt = ctg - 8;
                int t64 = rowb >> 6, ktp = (rowb >> 5) & 1, half = (rowb >> 4) & 1;
                int chunk = t64 * 8 + dt * 2 + ktp;
                union { _Float16 h[4]; unsigned long long u; } pk;
#pragma unroll
                for (int r = 0; r < 4; r++) pk.h[r] = (_Float16)(acc[s][ct][r] + bias);
                *(unsigned long long*)(Vh + (chunk * 64 + quad * 16 + m) * 8 + half * 4) = pk.u;
            }
        }
    }
}

// ---------------- Kernel 2: attention (this round: half-tile pipeline) ------
// grid = qblk(64) x ngrp(32); qt=1 (16q/wave, 64q/block); direct L2 loads, no
// barriers. Flat h = 0..2*NT-1 half-tiles (32 keys each), fully unrolled:
//   body(h): issue kk/vv loads(h+1)   [L2 latency starts]
//            exp/cvt(h)               [VALU, hides load latency]
//            QK MFMA (h+1)            [loads arrived]
//            oden+PV MFMA (h)         [no producer wait; 10-MFMA prio cluster]
// V double-buffered (vva/vvb, static parity selection); K single-buffered
// (dead after its QK). ~106 live VGPR < 128 cap of launch_bounds(256,4).
#define LDV_BLOCK(VARR, HN)                                                    \
    do {                                                                       \
        _Pragma("unroll")                                                      \
        for (int dt = 0; dt < 4; dt++)                                         \
            VARR[dt] = vh4[((HN) >> 1) * 512 + ((HN) & 1) * 64 + dt * 128 + l];\
    } while (0)

#define PV_BLOCK(VARR)                                                         \
    do {                                                                       \
        _Pragma("unroll")                                                      \
        for (int dt = 0; dt < 4; dt++) {                                       \
            union { uint4 u; half8v h; } vc; vc.u = VARR[dt];                  \
            oacc[dt] = __builtin_amdgcn_mfma_f32_16x16x32_f16(vc.h, pb8,       \
                                                              oacc[dt], 0, 0, 0);\
        }                                                                      \
    } while (0)

template <int NT>
__global__ __launch_bounds__(256, 4) void attn_k(const _Float16* __restrict__ Qh,
                                                 const _Float16* __restrict__ Kh,
                                                 const _Float16* __restrict__ Vh,
                                                 const int* __restrict__ mask,
                                                 _Float16* __restrict__ Np,
                                                 float* __restrict__ Dp,
                                                 int gshift) {
    __shared__ float T[4][16 * 68];   // wave-private epilogue transpose (17.4 KB)

    int tid = threadIdx.x, l = tid & 63, wv = tid >> 6;
    int m = l & 15, quad = l >> 4;
    int bid = blockIdx.x;
    int grp = bid & ((1 << gshift) - 1), qblk = bid >> gshift;
    int os = grp >> 2, b = grp & 3;
    int q0 = qblk * 64 + wv * 16;

    const int* maskb = mask + b * 4096 + os * (NT * 64);
    int az = 0;
#pragma unroll
    for (int i = 0; i < NT; i++) az |= (maskb[l + i * 64] == 0);
    const bool hasz = __any(az);

    int qt_g = (b * 4096 + q0) >> 4;
    half8v qf[2];
#pragma unroll
    for (int c = 0; c < 2; c++)
        qf[c] = *(const half8v*)(Qh + ((qt_g * 2 + c) * 64 + l) * 8);

    half8v ones8;
#pragma unroll
    for (int i = 0; i < 8; i++) ones8[i] = (_Float16)1.0f;

    int tb0 = (b * 64 + os * NT) * 512;   // uint4 idx of this slice's tile 0
    const uint4* kh4 = (const uint4*)Kh + tb0;
    const uint4* vh4 = (const uint4*)Vh + tb0;

    floatx4 oacc[4];
#pragma unroll
    for (int dt = 0; dt < 4; dt++) oacc[dt] = (floatx4)(0.f);
    floatx4 oden = (floatx4)(0.f);

    uint4 kk[4], vva[4], vvb[4];
    floatx4 sf[2];

    // prologue: load + QK for half-tile 0
#pragma unroll
    for (int i = 0; i < 4; i++) kk[i] = kh4[i * 64 + l];
    LDV_BLOCK(vva, 0);
#pragma unroll
    for (int se = 0; se < 2; se++) {
        union { uint4 u; half8v h; } k0, k1;
        k0.u = kk[se * 2 + 0]; k1.u = kk[se * 2 + 1];
        floatx4 s = (floatx4)(0.f);
        s = __builtin_amdgcn_mfma_f32_16x16x32_f16(k0.h, qf[0], s, 0, 0, 0);
        s = __builtin_amdgcn_mfma_f32_16x16x32_f16(k1.h, qf[1], s, 0, 0, 0);
        sf[se] = s;
    }

#pragma unroll
    for (int h = 0; h < 2 * NT; h++) {
        const bool more = (h + 1 < 2 * NT);
        if (more) {   // issue next half-tile's loads (L2 latency starts now)
#pragma unroll
            for (int i = 0; i < 4; i++) kk[i] = kh4[(h + 1) * 256 + i * 64 + l];
            if ((h & 1) == 0) LDV_BLOCK(vvb, h + 1); else LDV_BLOCK(vva, h + 1);
        }
        half8v pb8;   // finish(h): exp/cvt on VALU hides the load latency
        {
            union { fp16x2 h2[4]; half8v h8; } pu;
#pragma unroll
            for (int se = 0; se < 2; se++) {
                float p0 = EXP2(sf[se][0]), p1 = EXP2(sf[se][1]);
                float p2 = EXP2(sf[se][2]), p3 = EXP2(sf[se][3]);
                if (hasz) {   // post-softmax -inf fill (rare path)
                    int kg = h * 32 + se * 16 + quad * 4;
                    if (maskb[kg + 0] == 0) p0 = -__builtin_inff();
                    if (maskb[kg + 1] == 0) p1 = -__builtin_inff();
                    if (maskb[kg + 2] == 0) p2 = -__builtin_inff();
                    if (maskb[kg + 3] == 0) p3 = -__builtin_inff();
                }
                pu.h2[se * 2 + 0] = __builtin_amdgcn_cvt_pkrtz(p0, p1);
                pu.h2[se * 2 + 1] = __builtin_amdgcn_cvt_pkrtz(p2, p3);
            }
            pb8 = pu.h8;
        }
        __builtin_amdgcn_s_setprio(1);
        if (more) {   // QK(h+1): sf dead (consumed above), reuse registers
#pragma unroll
            for (int se = 0; se < 2; se++) {
                union { uint4 u; half8v h; } k0, k1;
                k0.u = kk[se * 2 + 0]; k1.u = kk[se * 2 + 1];
                floatx4 s = (floatx4)(0.f);
                s = __builtin_amdgcn_mfma_f32_16x16x32_f16(k0.h, qf[0], s, 0, 0, 0);
                s = __builtin_amdgcn_mfma_f32_16x16x32_f16(k1.h, qf[1], s, 0, 0, 0);
                sf[se] = s;
            }
        }
        oden = __builtin_amdgcn_mfma_f32_16x16x32_f16(ones8, pb8, oden, 0, 0, 0);
        if ((h & 1) == 0) PV_BLOCK(vva); else PV_BLOCK(vvb);
        __builtin_amdgcn_s_setprio(0);
    }

    // epilogue: den (lane-resident) + O^T transpose via wave-private LDS
    // (no barrier), fp16 out. lgkm-only waits: Np stores overlap.
    float* Tw = &T[wv][0];
    int rowb = os * 16384 + b * 4096 + q0;
    if (l < 16) Dp[rowb + l] = oden[0];
#pragma unroll
    for (int dt = 0; dt < 4; dt++)
#pragma unroll
        for (int r = 0; r < 4; r++)
            Tw[m * 68 + dt * 16 + quad * 4 + r] = oacc[dt][r];
    asm volatile("s_waitcnt lgkmcnt(0)" ::: "memory");   // LDS writes visible
    __builtin_amdgcn_sched_barrier(0);
#pragma unroll
    for (int g = 0; g < 4; g++) {
        int idx = g * 64 + l;
        int row = idx >> 4, c4 = (idx & 15) * 4;
        float4 v = *(const float4*)(Tw + row * 68 + c4);
        union { half4v h; unsigned long long u; } pk;
        pk.h[0] = (_Float16)v.x; pk.h[1] = (_Float16)v.y;
        pk.h[2] = (_Float16)v.z; pk.h[3] = (_Float16)v.w;
        *(unsigned long long*)(Np + (size_t)(rowb + row) * 64 + c4) = pk.u;
    }
}

// ---------------- Kernel 3: combine spl key-split partials (fp16 Np) --------
__global__ __launch_bounds__(256) void combine_k(const _Float16* __restrict__ Np,
                                                 const float* __restrict__ Dp,
                                                 float* __restrict__ out,
                                                 int spl) {
    int g4 = blockIdx.x * 256 + threadIdx.x;   // 262144 groups of 4 values
    int row = g4 >> 4;
    float4 nu = make_float4(0.f, 0.f, 0.f, 0.f);
    float d = 0.f;
    for (int sp = 0; sp < spl; sp++) {
        union { unsigned long long u; half4v h; } v;
        v.u = *(const unsigned long long*)(Np + ((size_t)sp << 20) + (size_t)g4 * 4);
        nu.x += (float)v.h[0]; nu.y += (float)v.h[1];
        nu.z += (float)v.h[2]; nu.w += (float)v.h[3];
        d += Dp[sp * 16384 + row];
    }
    float inv = 1.0f / d;
    ((float4*)out)[g4] = make_float4(nu.x * inv, nu.y * inv, nu.z * inv, nu.w * inv);
}

extern "C" void kernel_launch(void* const* d_in, const int* in_sizes, int n_in,
                              void* d_out, int out_size, void* d_ws, size_t ws_size,
                              hipStream_t stream) {
    const float* x  = (const float*)d_in[0];
    const int* mask = (const int*)d_in[1];
    const float* Wq = (const float*)d_in[2];
    const float* bq = (const float*)d_in[3];
    const float* Wk = (const float*)d_in[4];
    const float* bk = (const float*)d_in[5];
    const float* Wv = (const float*)d_in[6];
    const float* bv = (const float*)d_in[7];
    float* out = (float*)d_out;

    char* ws = (char*)d_ws;
    _Float16* Wt = (_Float16*)(ws);              // 192 KB frag-order
    _Float16* Qh = (_Float16*)(ws + 0x40000);    // 2 MB frag-order
    _Float16* Kh = (_Float16*)(ws + 0x240000);   // 2 MB frag-order
    _Float16* Vh = (_Float16*)(ws + 0x440000);   // 2 MB V^T frag-order
    float*    Dp = (float*)(ws + 0x640000);      // 512 KB [8][16384]
    _Float16* Np = (_Float16*)(ws + 0x740000);   // 8 * 2 MB fp16 partials

    // spl=8, qt=1, 64q/block: attn grid 2048 (64 qblk x 32 grp)
    wtrans_k<<<384, 256, 0, stream>>>(Wq, Wk, Wv, Wt);
    proj_k<<<512, 256, 0, stream>>>(x, Wt, bq, bk, bv, Qh, Kh, Vh);
    attn_k<8><<<64 * 32, 256, 0, stream>>>(Qh, Kh, Vh, mask, Np, Dp, 5);
    combine_k<<<1024, 256, 0, stream>>>(Np, Dp, out, 8);
}

// Round 11
// 121.184 us; speedup vs baseline: 1.1250x; 1.1250x over previous
//
#include <hip/hip_runtime.h>
#include <hip/hip_bf16.h>

typedef _Float16 half8v __attribute__((ext_vector_type(8)));
typedef _Float16 half4v __attribute__((ext_vector_type(4)));
typedef _Float16 half2v __attribute__((ext_vector_type(2)));
typedef __fp16   fp16x2 __attribute__((ext_vector_type(2)));
typedef __attribute__((ext_vector_type(4))) float floatx4;

#define LOG2E_OVER_8 0.18033688011112042f

// bare v_exp_f32 (scores are bounded: ocml's denorm/range fixup is dead work)
#if __has_builtin(__builtin_amdgcn_exp2f)
#define EXP2(x) __builtin_amdgcn_exp2f(x)
#else
#define EXP2(x) exp2f(x)
#endif

// ===== Frag-order layouts (verified r9-r17) =================================
// Kh chunk(t16,c): ((t16*2+c)*64 + quad*16 + m)*8 halves  (A-frag 16x16x32)
// Qh: same with m=q%16. Vh chunk(t64,dt,ktp): (((t64*8)+dt*2+ktp)*64+quad*16+m)*8
// Wt: ((ctg*16+kc)*64 + quad*16 + m)*8
// => every frag load = 64 lanes x contiguous 16B = 1 KB coalesced global read.
//
// PV k-permutation (verified r19): Vh's 8 halves/lane cover keys
// kappa(quad,j) = (j>>2)*16 + quad*4 + (j&3) of a 32-key half-tile; the P
// fragment built by concatenating two 16-key cvt_pkrtz quads has the SAME
// kappa order, so one mfma_16x16x32 computes the 32-key PV exactly.
//
// FINAL SESSION LEDGER (measured, baseline 137.9us):
//  WINS: PV@K32+ones-den -3.7 (r19); lb(256,4)+setprio+direct -5.1 (r20);
//        bare EXP2 + lgkm epilogue -4.7 (r21). Best = 122.07us (r26).
//  FALSIFIED: L2 K/V BW (staging neutral r18/r22); split traffic (spl4
//        neutral r23); LDS BW (2x reads free r23); proj 16-row +5 REGRESS
//        (r24); lb(256,6) spill disaster +17 (r25); qt=1 flat ILP pipeline
//        +14.3 REGRESS (r30: qt=1 costs 29% more MFMA instrs -- Q-reuse loss).
//  This file = r26 config, the measured optimum of this architecture.

// async global->LDS, 16B per lane (wave-uniform LDS base + lane*16)
__device__ __forceinline__ void gload_lds16(const void* g, void* l) {
    __builtin_amdgcn_global_load_lds(
        (const __attribute__((address_space(1))) void*)(unsigned long long)g,
        (__attribute__((address_space(3))) void*)(unsigned)(unsigned long long)l,
        16, 0, 0);
}

// ---------------- Kernel 0: W -> frag-order Wt fp16 -------------------------
__global__ __launch_bounds__(256) void wtrans_k(const float* __restrict__ Wq,
                                                const float* __restrict__ Wk,
                                                const float* __restrict__ Wv,
                                                _Float16* __restrict__ Wt) {
    int idx = blockIdx.x * 256 + threadIdx.x;   // 98304 = 3*512*64
    int p = idx >> 15, rem = idx & 32767;
    int k = rem >> 6;      // input row
    int n = rem & 63;      // input col (lane-fast -> coalesced read)
    const float* W = (p == 0) ? Wq : ((p == 1) ? Wk : Wv);
    int ctg = p * 4 + (n >> 4), m = n & 15;
    int kc = k >> 5, quad = (k >> 3) & 3, j = k & 7;
    Wt[(((ctg << 4) + kc) * 64 + (quad << 4) + m) * 8 + j] = (_Float16)W[k * 64 + n];
}

// ---------------- Kernel 1: QKV projection, 32-row blocks (r16 verbatim) ----
#define XS_STRIDE 536
__global__ __launch_bounds__(256) void proj_k(const float* __restrict__ x,
                                              const _Float16* __restrict__ Wt,
                                              const float* __restrict__ bq,
                                              const float* __restrict__ bk,
                                              const float* __restrict__ bv,
                                              _Float16* __restrict__ Qh,
                                              _Float16* __restrict__ Kh,
                                              _Float16* __restrict__ Vh) {
    __shared__ _Float16 xs[2][16 * XS_STRIDE];   // 34.3 KB

    int tid = threadIdx.x, l = tid & 63, wv = tid >> 6;
    int m = l & 15, quad = l >> 4;
    int row0 = blockIdx.x * 32;

#pragma unroll
    for (int s = 0; s < 2; s++)
#pragma unroll
        for (int i = 0; i < 8; i++) {
            int idx = tid + i * 256;
            int row = idx >> 7, c4 = idx & 127;
            float4 v = *(const float4*)(x + (row0 + s * 16 + row) * 512 + c4 * 4);
            union { half2v h[2]; uint2 u; } cv;
            cv.h[0][0] = (_Float16)v.x; cv.h[0][1] = (_Float16)v.y;
            cv.h[1][0] = (_Float16)v.z; cv.h[1][1] = (_Float16)v.w;
            *(uint2*)(xs[s] + row * XS_STRIDE + c4 * 4) = cv.u;
        }
    __syncthreads();

    const _Float16* arow0 = xs[0] + m * XS_STRIDE + quad * 8;
    const _Float16* arow1 = xs[1] + m * XS_STRIDE + quad * 8;

    floatx4 acc[2][3];
#pragma unroll
    for (int s = 0; s < 2; s++)
#pragma unroll
        for (int i = 0; i < 3; i++) acc[s][i] = (floatx4)(0.f);

#pragma unroll 4
    for (int kc = 0; kc < 16; kc++) {
        half8v a0 = *(const half8v*)(arow0 + kc * 32);
        half8v a1 = *(const half8v*)(arow1 + kc * 32);
#pragma unroll
        for (int ct = 0; ct < 3; ct++) {
            int ctg = wv * 3 + ct;
            half8v b = *(const half8v*)(Wt + (((ctg << 4) + kc) * 64 + l) * 8);
            acc[0][ct] = __builtin_amdgcn_mfma_f32_16x16x32_f16(a0, b, acc[0][ct], 0, 0, 0);
            acc[1][ct] = __builtin_amdgcn_mfma_f32_16x16x32_f16(a1, b, acc[1][ct], 0, 0, 0);
        }
    }

#pragma unroll
    for (int s = 0; s < 2; s++) {
        int rowb = row0 + s * 16;
#pragma unroll
        for (int ct = 0; ct < 3; ct++) {
            int ctg = wv * 3 + ct;
            int col = ctg * 16 + m;
            float bias = (ctg < 4) ? bq[col] : ((ctg < 8) ? bk[col - 64] : bv[col - 128]);
            if (ctg < 8) {
                _Float16* dst = (ctg < 4) ? Qh : Kh;
                float scl = (ctg < 4) ? LOG2E_OVER_8 : 1.0f;
                int dd = (ctg & 3) * 16 + m;
                int c = dd >> 5, quadQ = (dd >> 3) & 3, j = dd & 7;
#pragma unroll
                for (int r = 0; r < 4; r++) {
                    int row = rowb + quad * 4 + r;
                    int chunk = ((row >> 4) << 1) + c;
                    dst[(chunk * 64 + quadQ * 16 + (row & 15)) * 8 + j] =
                        (_Float16)((acc[s][ct][r] + bias) * scl);
                }
            } else {
                int dt = ctg - 8;
                int t64 = rowb >> 6, ktp = (rowb >> 5) & 1, half = (rowb >> 4) & 1;
                int chunk = t64 * 8 + dt * 2 + ktp;
                union { _Float16 h[4]; unsigned long long u; } pk;
#pragma unroll
                for (int r = 0; r < 4; r++) pk.h[r] = (_Float16)(acc[s][ct][r] + bias);
                *(unsigned long long*)(Vh + (chunk * 64 + quad * 16 + m) * 8 + half * 4) = pk.u;
            }
        }
    }
}

// ---------------- Kernel 2: attention (r22/r26 config = session best) -------
// grid = qblk x ngrp (ngrp = 32; bid & 31 -> XCD-pinned K/V slice).
// spl=8, qt=2 (32q/wave), NT=8; staged double-buffered K/V via global_load_lds;
// launch_bounds(256,4) -> VGPR<=128, 4 blocks/CU resident, no spills;
// setprio around MFMA clusters; bare v_exp_f32; kappa-PV@K32; ones-den MFMA;
// lgkm-only epilogue waits.
template <int NT>
__global__ __launch_bounds__(256, 4) void attn_k(const _Float16* __restrict__ Qh,
                                                 const _Float16* __restrict__ Kh,
                                                 const _Float16* __restrict__ Vh,
                                                 const int* __restrict__ mask,
                                                 _Float16* __restrict__ Np,
                                                 float* __restrict__ Dp,
                                                 int gshift) {
    __shared__ __align__(16) uint4 stage_lds[2][1024];   // [buf][K:0..511|V:512..1023] = 32 KB

    int tid = threadIdx.x, l = tid & 63, wv = tid >> 6;
    int m = l & 15, quad = l >> 4;
    int bid = blockIdx.x;
    int grp = bid & ((1 << gshift) - 1), qblk = bid >> gshift;
    int os = grp >> 2, b = grp & 3;
    int q0 = qblk * 128 + wv * 32;

    const int* maskb = mask + b * 4096 + os * (NT * 64);
    int az = 0;
#pragma unroll
    for (int i = 0; i < NT; i++) az |= (maskb[l + i * 64] == 0);
    const bool hasz = __any(az);

    int qt_g = (b * 4096 + q0) >> 4;
    half8v qf[2][2];
#pragma unroll
    for (int qt = 0; qt < 2; qt++)
#pragma unroll
        for (int c = 0; c < 2; c++)
            qf[qt][c] = *(const half8v*)(Qh + (((qt_g + qt) * 2 + c) * 64 + l) * 8);

    half8v ones8;
#pragma unroll
    for (int i = 0; i < 8; i++) ones8[i] = (_Float16)1.0f;

    int tb0 = (b * 64 + os * NT) * 512;   // uint4 idx of this slice's tile 0
    const uint4* kh4 = (const uint4*)Kh + tb0;
    const uint4* vh4 = (const uint4*)Vh + tb0;

    floatx4 oacc[2][4];
#pragma unroll
    for (int qt = 0; qt < 2; qt++)
#pragma unroll
        for (int dt = 0; dt < 4; dt++) oacc[qt][dt] = (floatx4)(0.f);
    floatx4 oden[2] = {(floatx4)(0.f), (floatx4)(0.f)};

    // prologue: stage tile 0 into buf 0 (each wave: 2x 1KB K + 2x 1KB V)
#pragma unroll
    for (int i = 0; i < 2; i++) {
        int idx = wv * 128 + i * 64 + l;
        gload_lds16(kh4 + idx, &stage_lds[0][0] + idx);
        gload_lds16(vh4 + idx, &stage_lds[0][512] + idx);
    }
    __syncthreads();   // implicit vmcnt(0): tile 0 resident

    for (int t = 0; t < NT; t++) {
        int cur = t & 1;
        if (t + 1 < NT) {   // issue next tile's staging; overlaps compute below
            const uint4* ksrc = kh4 + (t + 1) * 512;
            const uint4* vsrc = vh4 + (t + 1) * 512;
            uint4* kb = &stage_lds[cur ^ 1][0];
            uint4* vb = &stage_lds[cur ^ 1][512];
#pragma unroll
            for (int i = 0; i < 2; i++) {
                int idx = wv * 128 + i * 64 + l;
                gload_lds16(ksrc + idx, kb + idx);
                gload_lds16(vsrc + idx, vb + idx);
            }
        }
        const uint4* kt4 = &stage_lds[cur][0];
        const uint4* vt4 = &stage_lds[cur][512];
#pragma unroll
        for (int sp = 0; sp < 2; sp++) {   // 32-key half-tile
            union { uint4 u; half8v h; } kk[4];
#pragma unroll
            for (int i = 0; i < 4; i++)
                kk[i].u = kt4[(sp * 4 + i) * 64 + l];    // ds_read_b128, conflict-free
            uint4 vv[4];
#pragma unroll
            for (int dt = 0; dt < 4; dt++)
                vv[dt] = vt4[(dt * 2 + sp) * 64 + l];
            half8v pb8[2];
#pragma unroll
            for (int qt = 0; qt < 2; qt++) {
                union { fp16x2 h2[4]; half8v h8; } pu;
#pragma unroll
                for (int se = 0; se < 2; se++) {   // 16-key sub within half
                    floatx4 sf = (floatx4)(0.f);
                    __builtin_amdgcn_s_setprio(1);
                    sf = __builtin_amdgcn_mfma_f32_16x16x32_f16(kk[se * 2 + 0].h, qf[qt][0], sf, 0, 0, 0);
                    sf = __builtin_amdgcn_mfma_f32_16x16x32_f16(kk[se * 2 + 1].h, qf[qt][1], sf, 0, 0, 0);
                    __builtin_amdgcn_s_setprio(0);
                    float p0 = EXP2(sf[0]), p1 = EXP2(sf[1]);
                    float p2 = EXP2(sf[2]), p3 = EXP2(sf[3]);
                    if (hasz) {   // post-softmax -inf fill (rare path)
                        int kg = t * 64 + (sp * 2 + se) * 16 + quad * 4;
                        if (maskb[kg + 0] == 0) p0 = -__builtin_inff();
                        if (maskb[kg + 1] == 0) p1 = -__builtin_inff();
                        if (maskb[kg + 2] == 0) p2 = -__builtin_inff();
                        if (maskb[kg + 3] == 0) p3 = -__builtin_inff();
                    }
                    pu.h2[se * 2 + 0] = __builtin_amdgcn_cvt_pkrtz(p0, p1);
                    pu.h2[se * 2 + 1] = __builtin_amdgcn_cvt_pkrtz(p2, p3);
                }
                pb8[qt] = pu.h8;
            }
            __builtin_amdgcn_s_setprio(1);
            oden[0] = __builtin_amdgcn_mfma_f32_16x16x32_f16(ones8, pb8[0], oden[0], 0, 0, 0);
            oden[1] = __builtin_amdgcn_mfma_f32_16x16x32_f16(ones8, pb8[1], oden[1], 0, 0, 0);
#pragma unroll
            for (int dt = 0; dt < 4; dt++) {
                union { uint4 u; half8v h; } vc; vc.u = vv[dt];
                oacc[0][dt] = __builtin_amdgcn_mfma_f32_16x16x32_f16(vc.h, pb8[0], oacc[0][dt], 0, 0, 0);
                oacc[1][dt] = __builtin_amdgcn_mfma_f32_16x16x32_f16(vc.h, pb8[1], oacc[1][dt], 0, 0, 0);
            }
            __builtin_amdgcn_s_setprio(0);
        }
        __syncthreads();   // t+1 staging resident; protects buf reuse
    }

    // epilogue: den (lane-resident) + O^T transpose via wave-private LDS region
    // aliased onto the (now dead) stage buffer; final loop barrier ran, safe.
    float* Tw = (float*)&stage_lds[0][0] + wv * (16 * 68);
    int rowb = os * 16384 + b * 4096 + q0;
#pragma unroll
    for (int qt = 0; qt < 2; qt++) {
        if (l < 16) Dp[rowb + qt * 16 + l] = oden[qt][0];
#pragma unroll
        for (int dt = 0; dt < 4; dt++)
#pragma unroll
            for (int r = 0; r < 4; r++)
                Tw[m * 68 + dt * 16 + quad * 4 + r] = oacc[qt][dt][r];
        asm volatile("s_waitcnt lgkmcnt(0)" ::: "memory");   // LDS writes visible
        __builtin_amdgcn_sched_barrier(0);
#pragma unroll
        for (int g = 0; g < 4; g++) {
            int idx = g * 64 + l;
            int row = idx >> 4, c4 = (idx & 15) * 4;
            float4 v = *(const float4*)(Tw + row * 68 + c4);
            union { half4v h; unsigned long long u; } pk;
            pk.h[0] = (_Float16)v.x; pk.h[1] = (_Float16)v.y;
            pk.h[2] = (_Float16)v.z; pk.h[3] = (_Float16)v.w;
            *(unsigned long long*)(Np + (size_t)(rowb + qt * 16 + row) * 64 + c4) = pk.u;
        }
        asm volatile("s_waitcnt lgkmcnt(0)" ::: "memory");   // LDS reads done
        __builtin_amdgcn_sched_barrier(0);
    }
}

// ---------------- Kernel 3: combine spl key-split partials (fp16 Np) --------
__global__ __launch_bounds__(256) void combine_k(const _Float16* __restrict__ Np,
                                                 const float* __restrict__ Dp,
                                                 float* __restrict__ out,
                                                 int spl) {
    int g4 = blockIdx.x * 256 + threadIdx.x;   // 262144 groups of 4 values
    int row = g4 >> 4;
    float4 nu = make_float4(0.f, 0.f, 0.f, 0.f);
    float d = 0.f;
    for (int sp = 0; sp < spl; sp++) {
        union { unsigned long long u; half4v h; } v;
        v.u = *(const unsigned long long*)(Np + ((size_t)sp << 20) + (size_t)g4 * 4);
        nu.x += (float)v.h[0]; nu.y += (float)v.h[1];
        nu.z += (float)v.h[2]; nu.w += (float)v.h[3];
        d += Dp[sp * 16384 + row];
    }
    float inv = 1.0f / d;
    ((float4*)out)[g4] = make_float4(nu.x * inv, nu.y * inv, nu.z * inv, nu.w * inv);
}

extern "C" void kernel_launch(void* const* d_in, const int* in_sizes, int n_in,
                              void* d_out, int out_size, void* d_ws, size_t ws_size,
                              hipStream_t stream) {
    const float* x  = (const float*)d_in[0];
    const int* mask = (const int*)d_in[1];
    const float* Wq = (const float*)d_in[2];
    const float* bq = (const float*)d_in[3];
    const float* Wk = (const float*)d_in[4];
    const float* bk = (const float*)d_in[5];
    const float* Wv = (const float*)d_in[6];
    const float* bv = (const float*)d_in[7];
    float* out = (float*)d_out;

    char* ws = (char*)d_ws;
    _Float16* Wt = (_Float16*)(ws);              // 192 KB frag-order
    _Float16* Qh = (_Float16*)(ws + 0x40000);    // 2 MB frag-order
    _Float16* Kh = (_Float16*)(ws + 0x240000);   // 2 MB frag-order
    _Float16* Vh = (_Float16*)(ws + 0x440000);   // 2 MB V^T frag-order
    float*    Dp = (float*)(ws + 0x640000);      // 512 KB [8][16384]
    _Float16* Np = (_Float16*)(ws + 0x740000);   // 8 * 2 MB fp16 partials

    wtrans_k<<<384, 256, 0, stream>>>(Wq, Wk, Wv, Wt);
    proj_k<<<512, 256, 0, stream>>>(x, Wt, bq, bk, bv, Qh, Kh, Vh);
    attn_k<8><<<32 * 32, 256, 0, stream>>>(Qh, Kh, Vh, mask, Np, Dp, 5);
    combine_k<<<1024, 256, 0, stream>>>(Np, Dp, out, 8);
}